// Round 11
// baseline (153.038 us; speedup 1.0000x reference)
//
#include <hip/hip_runtime.h>
#include <stdint.h>

#define Bn 4
#define Cn 256
#define On 256
#define Gn 64
#define Hn 64
#define Wn 64
#define HWn 4096
#define EPSf 1e-5f

// workspace byte offsets (16B-aligned)
#define WS_XT    0u           // x NHWC bf16: 8388608
#define WS_OFF   8388608u     // off [b][pos][18] f32: 1179648
#define WS_PWB   9568256u     // pw bf16 [o][c]: 131072
#define WS_WT    9699328u     // off_w transposed [g][ty][54] f32: 41472

typedef __attribute__((ext_vector_type(8))) short short8;
typedef __attribute__((ext_vector_type(4))) float f4;

__device__ __forceinline__ unsigned int bfround(float f) {
    unsigned int u = __float_as_uint(f);
    u += 0x7FFFu + ((u >> 16) & 1u);
    return u >> 16;
}
__device__ __forceinline__ float blo(unsigned u) { return __uint_as_float(u << 16); }
__device__ __forceinline__ float bhi(unsigned u) { return __uint_as_float(u & 0xFFFF0000u); }

// ---------------- k_pre: x transpose + pw convert + weight transpose ----------------
__global__ __launch_bounds__(256, 4) void k_pre(const float* __restrict__ x,
                                                const float* __restrict__ pw_w,
                                                const float* __restrict__ off_w,
                                                char* __restrict__ ws)
{
    __shared__ float smem[4160];     // 64x65 tile
    int tid = threadIdx.x, bid = blockIdx.x;

    if (bid < 1024) {
        unsigned short* xt = (unsigned short*)(ws + WS_XT);
        int pt = bid & 63, ct = (bid >> 6) & 3, b = bid >> 8;
        int p0 = pt * 64, c0 = ct * 64;
        const f4* x4 = (const f4*)(x + (size_t)b * Cn * HWn);
        #pragma unroll
        for (int it = 0; it < 4; ++it) {
            int v = it * 256 + tid;
            int ci = v >> 4, pj = v & 15;
            f4 f = __builtin_nontemporal_load(&x4[(size_t)(c0 + ci) * 1024 + (p0 >> 2) + pj]);
            smem[ci * 65 + pj * 4 + 0] = f[0];
            smem[ci * 65 + pj * 4 + 1] = f[1];
            smem[ci * 65 + pj * 4 + 2] = f[2];
            smem[ci * 65 + pj * 4 + 3] = f[3];
        }
        __syncthreads();
        unsigned short* xtb = xt + (size_t)b * HWn * Cn;
        #pragma unroll
        for (int it = 0; it < 2; ++it) {
            int u = it * 256 + tid;
            int pi = u >> 3, cj = u & 7;
            float f[8];
            #pragma unroll
            for (int j = 0; j < 8; ++j)
                f[j] = smem[(cj * 8 + j) * 65 + pi];
            uint4 pk;
            pk.x = bfround(f[0]) | (bfround(f[1]) << 16);
            pk.y = bfround(f[2]) | (bfround(f[3]) << 16);
            pk.z = bfround(f[4]) | (bfround(f[5]) << 16);
            pk.w = bfround(f[6]) | (bfround(f[7]) << 16);
            *(uint4*)(xtb + (size_t)(p0 + pi) * Cn + c0 + cj * 8) = pk;
        }
        return;
    }
    if (bid < 1056) {
        // pw f32 -> bf16
        unsigned short* pwb = (unsigned short*)(ws + WS_PWB);
        const float4* p4 = (const float4*)pw_w;
        uint2* o2 = (uint2*)pwb;
        int base = (bid - 1024) * 512;
        #pragma unroll
        for (int i = 0; i < 2; ++i) {
            int id2 = base + i * 256 + tid;
            float4 f = p4[id2];
            uint2 pk;
            pk.x = bfround(f.x) | (bfround(f.y) << 16);
            pk.y = bfround(f.z) | (bfround(f.w) << 16);
            o2[id2] = pk;
        }
        return;
    }
    // off_w transpose -> ws [g][ty][tx*18+ch]
    {
        float* wT = (float*)(ws + WS_WT);
        for (int i = tid; i < 10368; i += 256) {
            int ch = i / 576;
            int rem = i - ch * 576;
            int g = rem / 9;
            int r9 = rem - g * 9;
            int ty = r9 / 3, tx = r9 - ty * 3;
            wT[(g * 3 + ty) * 54 + tx * 18 + ch] = off_w[i];
        }
    }
}

// ---------------- k_off: offset conv (G=64->18, 3x3, pad1) + BN + ReLU ----------------
// Weights read via wave-uniform loads from __restrict__ wT -> compiler scalarizes to s_load.
// No LDS weight staging (LDS-read throughput was the R6-R10 bottleneck here: 2592 ds_read/lane).
__global__ __launch_bounds__(256, 4) void k_off(const float* __restrict__ gf,
                                                const float* __restrict__ wT,
                                                const float* __restrict__ og,
                                                const float* __restrict__ obt,
                                                const float* __restrict__ om,
                                                const float* __restrict__ ov,
                                                float* __restrict__ off)
{
    __shared__ float sred[4 * 18 * 65];
    int tid = threadIdx.x;
    int h = blockIdx.x, b = blockIdx.y;
    int lane = tid & 63;
    int wvU = __builtin_amdgcn_readfirstlane(tid >> 6);   // 0..3 uniform

    float acc[18];
    #pragma unroll
    for (int ch = 0; ch < 18; ++ch) acc[ch] = 0.f;

    const float* gfb = gf + (size_t)b * Gn * HWn;
    for (int gi = 0; gi < 16; ++gi) {
        int g = wvU * 16 + gi;
        const float* gfg = gfb + (size_t)g * HWn;
        float rv[3], su[3], sd[3];
        #pragma unroll
        for (int r = 0; r < 3; ++r) {
            int y = h - 1 + r;
            rv[r] = ((unsigned)y < 64u) ? gfg[y * 64 + lane] : 0.f;
        }
        #pragma unroll
        for (int r = 0; r < 3; ++r) {
            float u = __shfl_up(rv[r], 1);   su[r] = (lane == 0)  ? 0.f : u;
            float d = __shfl_down(rv[r], 1); sd[r] = (lane == 63) ? 0.f : d;
        }
        #pragma unroll
        for (int ty = 0; ty < 3; ++ty) {
            const float* wrow = wT + (g * 3 + ty) * 54;   // uniform addr -> s_load
            #pragma unroll
            for (int ch = 0; ch < 18; ++ch)
                acc[ch] += wrow[ch] * su[ty] + wrow[18 + ch] * rv[ty] + wrow[36 + ch] * sd[ty];
        }
    }

    #pragma unroll
    for (int ch = 0; ch < 18; ++ch)
        sred[(wvU * 18 + ch) * 65 + lane] = acc[ch];
    __syncthreads();

    float* obp = off + (size_t)(b * HWn + h * 64) * 18;
    for (int i = tid; i < 1152; i += 256) {
        int w = i / 18, ch = i - w * 18;
        float v = sred[ch * 65 + w] + sred[(18 + ch) * 65 + w]
                + sred[(36 + ch) * 65 + w] + sred[(54 + ch) * 65 + w];
        float s = og[ch] * rsqrtf(ov[ch] + EPSf);
        v = (v - om[ch]) * s + obt[ch];
        obp[i] = v > 0.f ? v : 0.f;
    }
}

// ---------------- k_fuse: gather + depthwise -> LDS, MFMA pointwise + BN + ReLU ----------------
// 512 blocks x 512 thr; CONTIGUOUS mapping: consecutive bids share a 32-row band of one batch
// (R10 FETCH=8x full-xt falsified the bid%8->XCD round-robin assumption; chunked assignment assumed).
#define TLD 264   // t-tile row stride in shorts
__global__ __launch_bounds__(512, 6) void k_fuse(float* __restrict__ out,
                                                 const float* __restrict__ dw_w,
                                                 const float* __restrict__ bg,
                                                 const float* __restrict__ bb,
                                                 const float* __restrict__ bm,
                                                 const float* __restrict__ bv,
                                                 const char* __restrict__ ws)
{
    const unsigned short* __restrict__ xt  = (const unsigned short*)(ws + WS_XT);
    const unsigned short* __restrict__ pwb = (const unsigned short*)(ws + WS_PWB);
    const float* __restrict__ off = (const float*)(ws + WS_OFF);
    __shared__ float smeta[288 * 8];          // 9216 B
    __shared__ float sdw[9 * 256];            // 9216 B  [k][c]
    __shared__ unsigned short tl[32 * TLD];   // 16896 B

    int bid = blockIdx.x;
    int b = bid >> 7;
    int local = bid & 127;
    int h = local >> 1;
    int w0 = (local & 1) << 5;
    int tid = threadIdx.x;

    // stage dw (transposed) -> LDS
    for (int i = tid; i < 2304; i += 512) {
        int k = i >> 8, c = i & 255;
        sdw[i] = dw_w[c * 9 + k];
    }

    // ---- phase 1: bilinear meta for 32 positions x 9 taps ----
    if (tid < 288) {
        int k = tid >> 5, wl = tid & 31;
        int w = w0 + wl;
        int kyi = k / 3, kxi = k - kyi * 3;
        const float* op = off + ((size_t)(b * HWn + h * 64 + w)) * 18 + 2 * k;
        float dy = op[0], dx = op[1];
        float gy = (float)(h + (kyi - 1) * 2) + dy;
        float gx = (float)(w + (kxi - 1) * 2) + dx;
        float fy = floorf(gy), fx = floorf(gx);
        float wy = gy - fy, wx = gx - fx;
        int y0 = (int)fy, x0 = (int)fx;
        int y1 = y0 + 1, x1 = x0 + 1;
        float m00 = ((unsigned)y0 < 64u && (unsigned)x0 < 64u) ? 1.f : 0.f;
        float m01 = ((unsigned)y0 < 64u && (unsigned)x1 < 64u) ? 1.f : 0.f;
        float m10 = ((unsigned)y1 < 64u && (unsigned)x0 < 64u) ? 1.f : 0.f;
        float m11 = ((unsigned)y1 < 64u && (unsigned)x1 < 64u) ? 1.f : 0.f;
        int y0c = min(max(y0, 0), 63), y1c = min(max(y1, 0), 63);
        int x0c = min(max(x0, 0), 63), x1c = min(max(x1, 0), 63);
        float4 mw;
        mw.x = (1.f - wy) * (1.f - wx) * m00;
        mw.y = (1.f - wy) * wx * m01;
        mw.z = wy * (1.f - wx) * m10;
        mw.w = wy * wx * m11;
        float4 mo;
        mo.x = __int_as_float((y0c * 64 + x0c) << 9);   // *256ch *2B
        mo.y = __int_as_float((y0c * 64 + x1c) << 9);
        mo.z = __int_as_float((y1c * 64 + x0c) << 9);
        mo.w = __int_as_float((y1c * 64 + x1c) << 9);
        float4* s4w = (float4*)smeta;
        s4w[(k * 32 + wl) * 2] = mw;
        s4w[(k * 32 + wl) * 2 + 1] = mo;
    }
    __syncthreads();

    int lane = tid & 63, wave = tid >> 6;
    int half = lane >> 5, c8 = lane & 31;
    int c0 = c8 * 8;

    // ---- phase 2: gather + depthwise -> LDS t tile ----
    // k-loop deliberately NOT unrolled: keeps live VGPRs bounded (no scratch spill).
    const char* xb = (const char*)(xt + (size_t)b * HWn * Cn);
    int laneByte = c8 * 16;
    const float4* s4 = (const float4*)smeta;
    #pragma unroll
    for (int iter = 0; iter < 2; ++iter) {
        int wl = iter * 16 + wave * 2 + half;
        float acc[8];
        #pragma unroll
        for (int j = 0; j < 8; ++j) acc[j] = 0.f;
        #pragma unroll 1
        for (int k = 0; k < 9; ++k) {
            float4 mw = s4[(k * 32 + wl) * 2];
            float4 mo = s4[(k * 32 + wl) * 2 + 1];
            float4 d0 = *(const float4*)(&sdw[k * 256 + c0]);
            float4 d1 = *(const float4*)(&sdw[k * 256 + c0 + 4]);
            uint4 qA = *(const uint4*)(xb + __float_as_int(mo.x) + laneByte);
            uint4 qB = *(const uint4*)(xb + __float_as_int(mo.y) + laneByte);
            uint4 qC = *(const uint4*)(xb + __float_as_int(mo.z) + laneByte);
            uint4 qD = *(const uint4*)(xb + __float_as_int(mo.w) + laneByte);
            const unsigned* uA = (const unsigned*)&qA;
            const unsigned* uB = (const unsigned*)&qB;
            const unsigned* uC = (const unsigned*)&qC;
            const unsigned* uD = (const unsigned*)&qD;
            const float* dk0 = (const float*)&d0;
            const float* dk1 = (const float*)&d1;
            #pragma unroll
            for (int j = 0; j < 4; ++j) {
                const float* dkj = (j < 2) ? dk0 : dk1;
                int jj = (j & 1) * 2;
                float sl = mw.x * blo(uA[j]) + mw.y * blo(uB[j]) + mw.z * blo(uC[j]) + mw.w * blo(uD[j]);
                float sh = mw.x * bhi(uA[j]) + mw.y * bhi(uB[j]) + mw.z * bhi(uC[j]) + mw.w * bhi(uD[j]);
                acc[2 * j]     += sl * dkj[jj];
                acc[2 * j + 1] += sh * dkj[jj + 1];
            }
        }
        uint4 pk;
        pk.x = bfround(acc[0]) | (bfround(acc[1]) << 16);
        pk.y = bfround(acc[2]) | (bfround(acc[3]) << 16);
        pk.z = bfround(acc[4]) | (bfround(acc[5]) << 16);
        pk.w = bfround(acc[6]) | (bfround(acc[7]) << 16);
        *(uint4*)(&tl[wl * TLD + c0]) = pk;
    }
    __syncthreads();

    // ---- phase 3: 256x32x256 MFMA vs pw + BN + ReLU (nontemporal out) ----
    int m0 = wave * 32;
    int row = lane & 15, quad = lane >> 4;
    f4 acc[2][2];
    #pragma unroll
    for (int i = 0; i < 2; ++i)
        #pragma unroll
        for (int j = 0; j < 2; ++j)
            acc[i][j] = (f4){0.f, 0.f, 0.f, 0.f};

    #pragma unroll 2
    for (int kq = 0; kq < 8; ++kq) {
        int kk = kq * 32 + quad * 8;
        short8 a[2], bf[2];
        #pragma unroll
        for (int mt = 0; mt < 2; ++mt)
            a[mt] = *(const short8*)(pwb + (size_t)(m0 + mt * 16 + row) * Cn + kk);
        #pragma unroll
        for (int nt = 0; nt < 2; ++nt)
            bf[nt] = *(const short8*)(&tl[(nt * 16 + row) * TLD + kk]);
        #pragma unroll
        for (int mt = 0; mt < 2; ++mt)
            #pragma unroll
            for (int nt = 0; nt < 2; ++nt)
                acc[mt][nt] = __builtin_amdgcn_mfma_f32_16x16x32_bf16(a[mt], bf[nt], acc[mt][nt], 0, 0, 0);
    }

    float* obp = out + (size_t)b * On * HWn + h * 64 + w0;
    #pragma unroll
    for (int mt = 0; mt < 2; ++mt) {
        #pragma unroll
        for (int r = 0; r < 4; ++r) {
            int o = m0 + mt * 16 + quad * 4 + r;
            float s = bg[o] * rsqrtf(bv[o] + EPSf);
            float sh = bb[o] - bm[o] * s;
            #pragma unroll
            for (int nt = 0; nt < 2; ++nt) {
                float v = acc[mt][nt][r] * s + sh;
                v = v > 0.f ? v : 0.f;
                __builtin_nontemporal_store(v, &obp[(size_t)o * HWn + nt * 16 + row]);
            }
        }
    }
}

extern "C" void kernel_launch(void* const* d_in, const int* in_sizes, int n_in,
                              void* d_out, int out_size, void* d_ws, size_t ws_size,
                              hipStream_t stream)
{
    const float* x     = (const float*)d_in[0];
    const float* gf    = (const float*)d_in[1];
    const float* off_w = (const float*)d_in[2];
    const float* og    = (const float*)d_in[3];
    const float* ob    = (const float*)d_in[4];
    const float* om    = (const float*)d_in[5];
    const float* ov    = (const float*)d_in[6];
    const float* dw_w  = (const float*)d_in[7];
    const float* pw_w  = (const float*)d_in[8];
    const float* bg    = (const float*)d_in[9];
    const float* bb    = (const float*)d_in[10];
    const float* bm    = (const float*)d_in[11];
    const float* bv    = (const float*)d_in[12];
    float* out = (float*)d_out;
    char* ws = (char*)d_ws;

    hipLaunchKernelGGL(k_pre, dim3(1057), dim3(256), 0, stream, x, pw_w, off_w, ws);
    hipLaunchKernelGGL(k_off, dim3(Hn, Bn), dim3(256), 0, stream,
                       gf, (const float*)(ws + WS_WT), og, ob, om, ov,
                       (float*)(ws + WS_OFF));
    hipLaunchKernelGGL(k_fuse, dim3(512), dim3(512), 0, stream,
                       out, dw_w, bg, bb, bm, bv, ws);
}

// Round 12
// 140.079 us; speedup vs baseline: 1.0925x; 1.0925x over previous
//
#include <hip/hip_runtime.h>
#include <stdint.h>

#define Bn 4
#define Cn 256
#define On 256
#define Gn 64
#define Hn 64
#define Wn 64
#define HWn 4096
#define EPSf 1e-5f

// workspace byte offsets (16B-aligned)
#define WS_XT    0u           // x NHWC bf16: 8388608
#define WS_OFF   8388608u     // off [b][pos][18] f32: 1179648
#define WS_PWB   9568256u     // pw bf16 [o][c]: 131072

typedef __attribute__((ext_vector_type(8))) short short8;
typedef __attribute__((ext_vector_type(4))) float f4;

__device__ __forceinline__ unsigned int bfround(float f) {
    unsigned int u = __float_as_uint(f);
    u += 0x7FFFu + ((u >> 16) & 1u);
    return u >> 16;
}
__device__ __forceinline__ float blo(unsigned u) { return __uint_as_float(u << 16); }
__device__ __forceinline__ float bhi(unsigned u) { return __uint_as_float(u & 0xFFFF0000u); }

// ---------------- k_prep: x transpose (1024) + pw convert (32) + offset conv (256) ----------------
// Merged so HBM-bound transpose waves and VALU-bound conv waves co-schedule (one launch, no drain).
__global__ __launch_bounds__(256, 4) void k_prep(const float* __restrict__ x,
                                                 const float* __restrict__ pw_w,
                                                 const float* __restrict__ off_w,
                                                 const float* __restrict__ gf,
                                                 const float* __restrict__ og,
                                                 const float* __restrict__ obt,
                                                 const float* __restrict__ om,
                                                 const float* __restrict__ ov,
                                                 char* __restrict__ ws)
{
    __shared__ float smem[4680];     // union: 64x65 tile (4160) | sred 4*18*65 (4680)
    int tid = threadIdx.x, bid = blockIdx.x;

    if (bid < 1024) {
        // ---- x NCHW f32 -> NHWC bf16, 64x64 tile ----
        unsigned short* xt = (unsigned short*)(ws + WS_XT);
        int pt = bid & 63, ct = (bid >> 6) & 3, b = bid >> 8;
        int p0 = pt * 64, c0 = ct * 64;
        const f4* x4 = (const f4*)(x + (size_t)b * Cn * HWn);
        #pragma unroll
        for (int it = 0; it < 4; ++it) {
            int v = it * 256 + tid;
            int ci = v >> 4, pj = v & 15;
            f4 f = __builtin_nontemporal_load(&x4[(size_t)(c0 + ci) * 1024 + (p0 >> 2) + pj]);
            smem[ci * 65 + pj * 4 + 0] = f[0];
            smem[ci * 65 + pj * 4 + 1] = f[1];
            smem[ci * 65 + pj * 4 + 2] = f[2];
            smem[ci * 65 + pj * 4 + 3] = f[3];
        }
        __syncthreads();
        unsigned short* xtb = xt + (size_t)b * HWn * Cn;
        #pragma unroll
        for (int it = 0; it < 2; ++it) {
            int u = it * 256 + tid;
            int pi = u >> 3, cj = u & 7;
            float f[8];
            #pragma unroll
            for (int j = 0; j < 8; ++j)
                f[j] = smem[(cj * 8 + j) * 65 + pi];
            uint4 pk;
            pk.x = bfround(f[0]) | (bfround(f[1]) << 16);
            pk.y = bfround(f[2]) | (bfround(f[3]) << 16);
            pk.z = bfround(f[4]) | (bfround(f[5]) << 16);
            pk.w = bfround(f[6]) | (bfround(f[7]) << 16);
            *(uint4*)(xtb + (size_t)(p0 + pi) * Cn + c0 + cj * 8) = pk;
        }
        return;
    }
    if (bid < 1056) {
        // ---- pw f32 -> bf16 ----
        unsigned short* pwb = (unsigned short*)(ws + WS_PWB);
        const float4* p4 = (const float4*)pw_w;
        uint2* o2 = (uint2*)pwb;
        int base = (bid - 1024) * 512;
        #pragma unroll
        for (int i = 0; i < 2; ++i) {
            int id2 = base + i * 256 + tid;
            float4 f = p4[id2];
            uint2 pk;
            pk.x = bfround(f.x) | (bfround(f.y) << 16);
            pk.y = bfround(f.z) | (bfround(f.w) << 16);
            o2[id2] = pk;
        }
        return;
    }
    // ---- offset conv (G=64->18, 3x3, pad1) + BN + ReLU ----
    // Weights read via wave-uniform s_loads DIRECTLY from off_w [ch][g][ty][tx]
    // (no transposed copy needed -> no ordering dependency on other roles).
    {
        float* off = (float*)(ws + WS_OFF);
        int idx = bid - 1056;
        int h = idx & 63, b = idx >> 6;
        int lane = tid & 63;
        int wvU = __builtin_amdgcn_readfirstlane(tid >> 6);   // 0..3 uniform

        float acc[18];
        #pragma unroll
        for (int ch = 0; ch < 18; ++ch) acc[ch] = 0.f;

        const float* gfb = gf + (size_t)b * Gn * HWn;
        for (int gi = 0; gi < 16; ++gi) {
            int g = wvU * 16 + gi;
            const float* gfg = gfb + (size_t)g * HWn;
            float rv[3], su[3], sd[3];
            #pragma unroll
            for (int r = 0; r < 3; ++r) {
                int y = h - 1 + r;
                rv[r] = ((unsigned)y < 64u) ? gfg[y * 64 + lane] : 0.f;
            }
            #pragma unroll
            for (int r = 0; r < 3; ++r) {
                float u = __shfl_up(rv[r], 1);   su[r] = (lane == 0)  ? 0.f : u;
                float d = __shfl_down(rv[r], 1); sd[r] = (lane == 63) ? 0.f : d;
            }
            #pragma unroll
            for (int ty = 0; ty < 3; ++ty) {
                const float* wb = off_w + g * 9 + ty * 3;     // + ch*576 + tx
                #pragma unroll
                for (int ch = 0; ch < 18; ++ch)
                    acc[ch] += wb[ch * 576 + 0] * su[ty]
                             + wb[ch * 576 + 1] * rv[ty]
                             + wb[ch * 576 + 2] * sd[ty];
            }
        }

        #pragma unroll
        for (int ch = 0; ch < 18; ++ch)
            smem[(wvU * 18 + ch) * 65 + lane] = acc[ch];
        __syncthreads();

        float* obp = off + (size_t)(b * HWn + h * 64) * 18;
        for (int i = tid; i < 1152; i += 256) {
            int w = i / 18, ch = i - w * 18;
            float v = smem[ch * 65 + w] + smem[(18 + ch) * 65 + w]
                    + smem[(36 + ch) * 65 + w] + smem[(54 + ch) * 65 + w];
            float s = og[ch] * rsqrtf(ov[ch] + EPSf);
            v = (v - om[ch]) * s + obt[ch];
            obp[i] = v > 0.f ? v : 0.f;
        }
    }
}

// ---------------- k_fuse: gather + depthwise -> LDS, MFMA pointwise + BN + ReLU ----------------
// R10 measured-best config: %8 swizzle, (512,4), rolled k-loop, nt stores.
#define TLD 264   // t-tile row stride in shorts
__global__ __launch_bounds__(512, 4) void k_fuse(float* __restrict__ out,
                                                 const float* __restrict__ dw_w,
                                                 const float* __restrict__ bg,
                                                 const float* __restrict__ bb,
                                                 const float* __restrict__ bm,
                                                 const float* __restrict__ bv,
                                                 const char* __restrict__ ws)
{
    const unsigned short* __restrict__ xt  = (const unsigned short*)(ws + WS_XT);
    const unsigned short* __restrict__ pwb = (const unsigned short*)(ws + WS_PWB);
    const float* __restrict__ off = (const float*)(ws + WS_OFF);
    __shared__ float smeta[288 * 8];          // 9216 B
    __shared__ float sdw[9 * 256];            // 9216 B  [k][c]
    __shared__ unsigned short tl[32 * TLD];   // 16896 B

    int bid = blockIdx.x;
    int xcd = bid & 7, slot = bid >> 3;
    int b = xcd >> 1;
    int h = ((xcd & 1) << 5) | (slot >> 1);
    int w0 = (slot & 1) << 5;
    int tid = threadIdx.x;

    // stage dw (transposed) -> LDS
    for (int i = tid; i < 2304; i += 512) {
        int k = i >> 8, c = i & 255;
        sdw[i] = dw_w[c * 9 + k];
    }

    // ---- phase 1: bilinear meta for 32 positions x 9 taps ----
    if (tid < 288) {
        int k = tid >> 5, wl = tid & 31;
        int w = w0 + wl;
        int kyi = k / 3, kxi = k - kyi * 3;
        const float* op = off + ((size_t)(b * HWn + h * 64 + w)) * 18 + 2 * k;
        float dy = op[0], dx = op[1];
        float gy = (float)(h + (kyi - 1) * 2) + dy;
        float gx = (float)(w + (kxi - 1) * 2) + dx;
        float fy = floorf(gy), fx = floorf(gx);
        float wy = gy - fy, wx = gx - fx;
        int y0 = (int)fy, x0 = (int)fx;
        int y1 = y0 + 1, x1 = x0 + 1;
        float m00 = ((unsigned)y0 < 64u && (unsigned)x0 < 64u) ? 1.f : 0.f;
        float m01 = ((unsigned)y0 < 64u && (unsigned)x1 < 64u) ? 1.f : 0.f;
        float m10 = ((unsigned)y1 < 64u && (unsigned)x0 < 64u) ? 1.f : 0.f;
        float m11 = ((unsigned)y1 < 64u && (unsigned)x1 < 64u) ? 1.f : 0.f;
        int y0c = min(max(y0, 0), 63), y1c = min(max(y1, 0), 63);
        int x0c = min(max(x0, 0), 63), x1c = min(max(x1, 0), 63);
        float4 mw;
        mw.x = (1.f - wy) * (1.f - wx) * m00;
        mw.y = (1.f - wy) * wx * m01;
        mw.z = wy * (1.f - wx) * m10;
        mw.w = wy * wx * m11;
        float4 mo;
        mo.x = __int_as_float((y0c * 64 + x0c) << 9);   // *256ch *2B
        mo.y = __int_as_float((y0c * 64 + x1c) << 9);
        mo.z = __int_as_float((y1c * 64 + x0c) << 9);
        mo.w = __int_as_float((y1c * 64 + x1c) << 9);
        float4* s4w = (float4*)smeta;
        s4w[(k * 32 + wl) * 2] = mw;
        s4w[(k * 32 + wl) * 2 + 1] = mo;
    }
    __syncthreads();

    int lane = tid & 63, wave = tid >> 6;
    int half = lane >> 5, c8 = lane & 31;
    int c0 = c8 * 8;

    // ---- phase 2: gather + depthwise -> LDS t tile ----
    // k-loop deliberately NOT unrolled: keeps live VGPRs bounded (no scratch spill).
    const char* xb = (const char*)(xt + (size_t)b * HWn * Cn);
    int laneByte = c8 * 16;
    const float4* s4 = (const float4*)smeta;
    #pragma unroll
    for (int iter = 0; iter < 2; ++iter) {
        int wl = iter * 16 + wave * 2 + half;
        float acc[8];
        #pragma unroll
        for (int j = 0; j < 8; ++j) acc[j] = 0.f;
        #pragma unroll 1
        for (int k = 0; k < 9; ++k) {
            float4 mw = s4[(k * 32 + wl) * 2];
            float4 mo = s4[(k * 32 + wl) * 2 + 1];
            float4 d0 = *(const float4*)(&sdw[k * 256 + c0]);
            float4 d1 = *(const float4*)(&sdw[k * 256 + c0 + 4]);
            uint4 qA = *(const uint4*)(xb + __float_as_int(mo.x) + laneByte);
            uint4 qB = *(const uint4*)(xb + __float_as_int(mo.y) + laneByte);
            uint4 qC = *(const uint4*)(xb + __float_as_int(mo.z) + laneByte);
            uint4 qD = *(const uint4*)(xb + __float_as_int(mo.w) + laneByte);
            const unsigned* uA = (const unsigned*)&qA;
            const unsigned* uB = (const unsigned*)&qB;
            const unsigned* uC = (const unsigned*)&qC;
            const unsigned* uD = (const unsigned*)&qD;
            const float* dk0 = (const float*)&d0;
            const float* dk1 = (const float*)&d1;
            #pragma unroll
            for (int j = 0; j < 4; ++j) {
                const float* dkj = (j < 2) ? dk0 : dk1;
                int jj = (j & 1) * 2;
                float sl = mw.x * blo(uA[j]) + mw.y * blo(uB[j]) + mw.z * blo(uC[j]) + mw.w * blo(uD[j]);
                float sh = mw.x * bhi(uA[j]) + mw.y * bhi(uB[j]) + mw.z * bhi(uC[j]) + mw.w * bhi(uD[j]);
                acc[2 * j]     += sl * dkj[jj];
                acc[2 * j + 1] += sh * dkj[jj + 1];
            }
        }
        uint4 pk;
        pk.x = bfround(acc[0]) | (bfround(acc[1]) << 16);
        pk.y = bfround(acc[2]) | (bfround(acc[3]) << 16);
        pk.z = bfround(acc[4]) | (bfround(acc[5]) << 16);
        pk.w = bfround(acc[6]) | (bfround(acc[7]) << 16);
        *(uint4*)(&tl[wl * TLD + c0]) = pk;
    }
    __syncthreads();

    // ---- phase 3: 256x32x256 MFMA vs pw + BN + ReLU (nontemporal out) ----
    int m0 = wave * 32;
    int row = lane & 15, quad = lane >> 4;
    f4 acc[2][2];
    #pragma unroll
    for (int i = 0; i < 2; ++i)
        #pragma unroll
        for (int j = 0; j < 2; ++j)
            acc[i][j] = (f4){0.f, 0.f, 0.f, 0.f};

    #pragma unroll 2
    for (int kq = 0; kq < 8; ++kq) {
        int kk = kq * 32 + quad * 8;
        short8 a[2], bf[2];
        #pragma unroll
        for (int mt = 0; mt < 2; ++mt)
            a[mt] = *(const short8*)(pwb + (size_t)(m0 + mt * 16 + row) * Cn + kk);
        #pragma unroll
        for (int nt = 0; nt < 2; ++nt)
            bf[nt] = *(const short8*)(&tl[(nt * 16 + row) * TLD + kk]);
        #pragma unroll
        for (int mt = 0; mt < 2; ++mt)
            #pragma unroll
            for (int nt = 0; nt < 2; ++nt)
                acc[mt][nt] = __builtin_amdgcn_mfma_f32_16x16x32_bf16(a[mt], bf[nt], acc[mt][nt], 0, 0, 0);
    }

    float* obp = out + (size_t)b * On * HWn + h * 64 + w0;
    #pragma unroll
    for (int mt = 0; mt < 2; ++mt) {
        #pragma unroll
        for (int r = 0; r < 4; ++r) {
            int o = m0 + mt * 16 + quad * 4 + r;
            float s = bg[o] * rsqrtf(bv[o] + EPSf);
            float sh = bb[o] - bm[o] * s;
            #pragma unroll
            for (int nt = 0; nt < 2; ++nt) {
                float v = acc[mt][nt][r] * s + sh;
                v = v > 0.f ? v : 0.f;
                __builtin_nontemporal_store(v, &obp[(size_t)o * HWn + nt * 16 + row]);
            }
        }
    }
}

extern "C" void kernel_launch(void* const* d_in, const int* in_sizes, int n_in,
                              void* d_out, int out_size, void* d_ws, size_t ws_size,
                              hipStream_t stream)
{
    const float* x     = (const float*)d_in[0];
    const float* gf    = (const float*)d_in[1];
    const float* off_w = (const float*)d_in[2];
    const float* og    = (const float*)d_in[3];
    const float* ob    = (const float*)d_in[4];
    const float* om    = (const float*)d_in[5];
    const float* ov    = (const float*)d_in[6];
    const float* dw_w  = (const float*)d_in[7];
    const float* pw_w  = (const float*)d_in[8];
    const float* bg    = (const float*)d_in[9];
    const float* bb    = (const float*)d_in[10];
    const float* bm    = (const float*)d_in[11];
    const float* bv    = (const float*)d_in[12];
    float* out = (float*)d_out;
    char* ws = (char*)d_ws;

    hipLaunchKernelGGL(k_prep, dim3(1312), dim3(256), 0, stream,
                       x, pw_w, off_w, gf, og, ob, om, ov, ws);
    hipLaunchKernelGGL(k_fuse, dim3(512), dim3(512), 0, stream,
                       out, dw_w, bg, bb, bm, bv, ws);
}